// Round 1
// baseline (147.210 us; speedup 1.0000x reference)
//
#include <hip/hip_runtime.h>
#include <math.h>

#define NP 1024          // proposals
#define NC 81            // classes incl background
#define CF 80            // foreground classes
#define DET 100          // detections per image
#define SCORE_THRESH 0.05f
#define NMS_THRESH 0.5f
#define BBOX_CLIP 4.135166556742356f   // log(1000/16)
#define IMG_W 1333
#define IMG_H 800

#define NCAND (CF * DET)   // 8000 max candidates (fixed per-class slots)

// ---------------------------------------------------------------------------
// Kernel A: per-class fused softmax + threshold-compact + sort + decode + NMS.
// 80 blocks x 256 threads (1 class per block).
//
// Phase A replicates kernel-1's softmax BIT-EXACTLY (proven absmax 0.0):
//   - stage logits rows into LDS in 4 chunks of 256 rows (coalesced float4)
//   - per-thread row softmax: serial fmax (exact any order), expf per class,
//     then the EXACT butterfly-tree sum association of the old wave kernel:
//     base a[i] = e_i + e_{64+i} (i<17; +0.0f elsewhere is bitwise identity),
//     then a[i] += a[i+off] for off = 32,16,8,4,2,1.
//   - score = expf(x[cls+1]-m) / sum   (same ops, same inputs -> same bits)
//
// Phase B is the previous kernel's fast/slow path with 256-thread strides.
// Output: deterministic slots gkeys/gboxes[cls*DET + kr] + gcnt[cls].
// No global atomics, no zero-init dependency (all 80 blocks write gcnt).
// ---------------------------------------------------------------------------
__global__ __launch_bounds__(256, 1) void
class_nms_fused(const float* __restrict__ logits,
                const float* __restrict__ rel,
                const float* __restrict__ props,
                unsigned long long* __restrict__ gkeys,
                float4* __restrict__ gboxes,
                int* __restrict__ gcnt) {
    const int cls = blockIdx.x;   // fg class (reference class = cls+1)
    const int tid = threadIdx.x;  // 0..255

    // stage (phase A) unions with key/vbox/supp (phase B); s[] stays live.
    __shared__ __align__(16) unsigned char smem[256 * NC * 4];   // 82944 B
    __shared__ __align__(16) float s[NP];                        // class scores
    __shared__ int cntSh;
    __shared__ int keptRank[DET];
    __shared__ int keptCnt;

    if (tid == 0) cntSh = 0;

    // ---------------- Phase A: class-cls scores for all 1024 proposals ------
    float* stage = (float*)smem;
    #pragma unroll 1
    for (int ch = 0; ch < 4; ++ch) {
        const float4* src = (const float4*)(logits + ch * 256 * NC);
        float4* dst = (float4*)stage;
        for (int v = tid; v < (256 * NC) / 4; v += 256) dst[v] = src[v];
        __syncthreads();

        const float* row = stage + tid * NC;   // bank stride 81: conflict-free
        float xv[NC];
        #pragma unroll
        for (int c = 0; c < NC; ++c) xv[c] = row[c];

        float m = xv[0];
        #pragma unroll
        for (int c = 1; c < NC; ++c) m = fmaxf(m, xv[c]);   // max: exact

        #pragma unroll
        for (int c = 0; c < NC; ++c) xv[c] = expf(xv[c] - m);

        // exact butterfly-tree sum (old wave kernel's association)
        #pragma unroll
        for (int i = 0; i < 17; ++i) xv[i] += xv[64 + i];
        #pragma unroll
        for (int i = 0; i < 32; ++i) xv[i] += xv[i + 32];
        #pragma unroll
        for (int i = 0; i < 16; ++i) xv[i] += xv[i + 16];
        #pragma unroll
        for (int i = 0; i < 8; ++i)  xv[i] += xv[i + 8];
        #pragma unroll
        for (int i = 0; i < 4; ++i)  xv[i] += xv[i + 4];
        xv[0] += xv[2]; xv[1] += xv[3];
        xv[0] += xv[1];
        const float sum = xv[0];

        // numerator recomputed (identical bits; avoids dynamic reg index)
        const float num = expf(row[cls + 1] - m);
        s[ch * 256 + tid] = num / sum;
        __syncthreads();
    }

    // ---------------- Phase B: compact -> sort -> decode -> NMS -------------
    unsigned long long* key = (unsigned long long*)smem;             // 8 KB
    float4* vbox = (float4*)(smem + 8192);                           // 16 KB
    unsigned char* supp = (unsigned char*)(smem + 8192 + 16384);     // 1 KB

    {
        const float4 v = ((const float4*)s)[tid];   // 4 scores per thread
        const int id0 = tid * 4;
        if (v.x > SCORE_THRESH) { int p = atomicAdd(&cntSh, 1); key[p] = ((unsigned long long)__float_as_uint(v.x) << 16) | (unsigned long long)(1023 - (id0 + 0)); }
        if (v.y > SCORE_THRESH) { int p = atomicAdd(&cntSh, 1); key[p] = ((unsigned long long)__float_as_uint(v.y) << 16) | (unsigned long long)(1023 - (id0 + 1)); }
        if (v.z > SCORE_THRESH) { int p = atomicAdd(&cntSh, 1); key[p] = ((unsigned long long)__float_as_uint(v.z) << 16) | (unsigned long long)(1023 - (id0 + 2)); }
        if (v.w > SCORE_THRESH) { int p = atomicAdd(&cntSh, 1); key[p] = ((unsigned long long)__float_as_uint(v.w) << 16) | (unsigned long long)(1023 - (id0 + 3)); }
    }
    __syncthreads();
    const int cnt = cntSh;
    if (cnt == 0) { if (tid == 0) gcnt[cls] = 0; return; }

    if (cnt <= 64) {
        // ================== FAST PATH: cnt<=64 (wave 0 active) ==============
        unsigned long long my = 0ull;
        int rk = 0;
        if (tid < cnt) {
            my = key[tid];
            for (int i = 0; i < cnt; ++i) rk += (key[i] > my) ? 1 : 0;
        }
        __syncthreads();
        if (tid < cnt) key[rk] = my;
        __syncthreads();

        if (tid < cnt) {
            const int id = 1023 - (int)(key[tid] & 0xFFFFull);
            const float4 p = ((const float4*)props)[id];
            const float w  = p.z - p.x + 1.0f;
            const float h  = p.w - p.y + 1.0f;
            const float cx = p.x + 0.5f * w;
            const float cy = p.y + 0.5f * h;

            const float4 r = ((const float4*)rel)[id * NC + (cls + 1)];
            const float dx = r.x / 10.0f;
            const float dy = r.y / 10.0f;
            const float dw = fminf(r.z / 5.0f, BBOX_CLIP);
            const float dh = fminf(r.w / 5.0f, BBOX_CLIP);

            const float pcx = dx * w + cx;
            const float pcy = dy * h + cy;
            const float pw  = expf(dw) * w;
            const float ph  = expf(dh) * h;

            float bx1 = pcx - 0.5f * pw;
            float by1 = pcy - 0.5f * ph;
            float bx2 = pcx + 0.5f * pw - 1.0f;
            float by2 = pcy + 0.5f * ph - 1.0f;

            bx1 = fminf(fmaxf(bx1, 0.0f), (float)(IMG_W - 1));
            bx2 = fminf(fmaxf(bx2, 0.0f), (float)(IMG_W - 1));
            by1 = fminf(fmaxf(by1, 0.0f), (float)(IMG_H - 1));
            by2 = fminf(fmaxf(by2, 0.0f), (float)(IMG_H - 1));

            vbox[tid] = make_float4(bx1, by1, bx2, by2);
        }
        __syncthreads();

        unsigned long long mymask = 0ull;
        if (tid < cnt) {
            const float4 bj = vbox[tid];
            const float areaj = (bj.z - bj.x + 1.0f) * (bj.w - bj.y + 1.0f);
            for (int i = 0; i < tid; ++i) {
                const float4 bi = vbox[i];
                const float areai = (bi.z - bi.x + 1.0f) * (bi.w - bi.y + 1.0f);
                const float ltx = fmaxf(bi.x, bj.x);
                const float lty = fmaxf(bi.y, bj.y);
                const float rbx = fminf(bi.z, bj.z);
                const float rby = fminf(bi.w, bj.w);
                const float wq = fmaxf(rbx - ltx + 1.0f, 0.0f);
                const float hq = fmaxf(rby - lty + 1.0f, 0.0f);
                const float inter = wq * hq;
                const float iou = inter / (areai + areaj - inter);
                if (iou > NMS_THRESH) mymask |= (1ull << i);
            }
        }
        // resolve in every wave; only wave 0 (tid<cnt, tid==0) results are used
        unsigned long long suppbits = 0ull;
        for (int i = 0; i < cnt; ++i) {
            if (!((suppbits >> i) & 1ull)) {
                const unsigned long long vote = __ballot((mymask >> i) & 1ull);
                suppbits |= vote;
            }
        }
        unsigned long long kb = ~suppbits;
        if (cnt < 64) kb &= ((1ull << cnt) - 1ull);
        const int c2 = __popcll(kb);

        if (tid == 0) gcnt[cls] = c2;
        if (tid < cnt && !((suppbits >> tid) & 1ull)) {
            const int kr = __popcll(kb & ((1ull << tid) - 1ull));
            const int slot = cls * DET + kr;
            const unsigned int bits = (unsigned int)(key[tid] >> 16);
            gkeys[slot] = ((unsigned long long)bits << 16) |
                          (unsigned long long)(65535 - slot);
            gboxes[slot] = vbox[tid];
        }
        return;
    }

    // ===================== SLOW PATH: cnt>64 (256-thread strides) ===========
    int msz = 1;
    while (msz < cnt) msz <<= 1;
    for (int t = cnt + tid; t < msz; t += 256) key[t] = 0ull;
    __syncthreads();

    for (int k = 2; k <= msz; k <<= 1) {
        for (int jj = k >> 1; jj > 0; jj >>= 1) {
            for (int t = tid; t < msz; t += 256) {
                const int ixj = t ^ jj;
                if (ixj > t) {
                    const unsigned long long a = key[t], b = key[ixj];
                    const bool tAfter = (a < b);
                    const bool dirAsc = ((t & k) == 0);
                    if (dirAsc ? tAfter : !tAfter) { key[t] = b; key[ixj] = a; }
                }
            }
            __syncthreads();
        }
    }

    for (int t = tid; t < cnt; t += 256) {
        const int id = 1023 - (int)(key[t] & 0xFFFFull);
        const float4 p = ((const float4*)props)[id];
        const float w  = p.z - p.x + 1.0f;
        const float h  = p.w - p.y + 1.0f;
        const float cx = p.x + 0.5f * w;
        const float cy = p.y + 0.5f * h;

        const float4 r = ((const float4*)rel)[id * NC + (cls + 1)];
        const float dx = r.x / 10.0f;
        const float dy = r.y / 10.0f;
        const float dw = fminf(r.z / 5.0f, BBOX_CLIP);
        const float dh = fminf(r.w / 5.0f, BBOX_CLIP);

        const float pcx = dx * w + cx;
        const float pcy = dy * h + cy;
        const float pw  = expf(dw) * w;
        const float ph  = expf(dh) * h;

        float bx1 = pcx - 0.5f * pw;
        float by1 = pcy - 0.5f * ph;
        float bx2 = pcx + 0.5f * pw - 1.0f;
        float by2 = pcy + 0.5f * ph - 1.0f;

        bx1 = fminf(fmaxf(bx1, 0.0f), (float)(IMG_W - 1));
        bx2 = fminf(fmaxf(bx2, 0.0f), (float)(IMG_W - 1));
        by1 = fminf(fmaxf(by1, 0.0f), (float)(IMG_H - 1));
        by2 = fminf(fmaxf(by2, 0.0f), (float)(IMG_H - 1));

        vbox[t] = make_float4(bx1, by1, bx2, by2);
        supp[t] = 0;
    }
    __syncthreads();

    for (int i = 0; i < cnt; ++i) {
        if (!supp[i]) {
            const float4 bi = vbox[i];
            const float areai = (bi.z - bi.x + 1.0f) * (bi.w - bi.y + 1.0f);
            for (int t = i + 1 + tid; t < cnt; t += 256) {
                const float4 bj = vbox[t];
                const float areaj = (bj.z - bj.x + 1.0f) * (bj.w - bj.y + 1.0f);
                const float ltx = fmaxf(bi.x, bj.x);
                const float lty = fmaxf(bi.y, bj.y);
                const float rbx = fminf(bi.z, bj.z);
                const float rby = fminf(bi.w, bj.w);
                const float wq = fmaxf(rbx - ltx + 1.0f, 0.0f);
                const float hq = fmaxf(rby - lty + 1.0f, 0.0f);
                const float inter = wq * hq;
                const float iou = inter / (areai + areaj - inter);
                if (iou > NMS_THRESH) supp[t] = 1;
            }
        }
        __syncthreads();
    }

    if (tid == 0) {
        int c2 = 0;
        for (int r = 0; r < cnt && c2 < DET; ++r)
            if (!supp[r]) keptRank[c2++] = r;
        keptCnt = c2;
        gcnt[cls] = c2;
    }
    __syncthreads();

    const int kc = keptCnt;
    for (int t = tid; t < kc; t += 256) {
        const int r = keptRank[t];
        const int slot = cls * DET + t;
        const unsigned int bits = (unsigned int)(key[r] >> 16);
        gkeys[slot] = ((unsigned long long)bits << 16) |
                      (unsigned long long)(65535 - slot);
        gboxes[slot] = vbox[r];
    }
}

// ---------------------------------------------------------------------------
// Kernel B: gather per-class segments (prefix over gcnt) -> rank-count topk.
// 32 blocks x 256 threads. Block 0 zero-fills output ranks in [K, DET).
// Ranks dense & unique -> exactly one writer per output slot.
// ---------------------------------------------------------------------------
__global__ __launch_bounds__(256) void
topk_rank_kernel(const unsigned long long* __restrict__ gkeys,
                 const float4* __restrict__ gboxes,
                 const int* __restrict__ gcnt,
                 float* __restrict__ out) {
    __shared__ __align__(16) unsigned long long keysh[NCAND];   // 62.5 KB
    __shared__ int cshare[CF];
    __shared__ int base[CF + 1];

    const int tid = threadIdx.x;
    if (tid < CF) cshare[tid] = gcnt[tid];
    __syncthreads();
    if (tid == 0) {
        int acc = 0;
        #pragma unroll 1
        for (int c = 0; c < CF; ++c) { base[c] = acc; acc += cshare[c]; }
        base[CF] = acc;
    }
    __syncthreads();
    const int K = base[CF];

    if (blockIdx.x == 0) {   // zero-fill unwritten output ranks (K < DET case)
        for (int r = K + tid; r < DET; r += 256) {
            out[r * 4 + 0] = 0.0f; out[r * 4 + 1] = 0.0f;
            out[r * 4 + 2] = 0.0f; out[r * 4 + 3] = 0.0f;
            out[4 * DET + r] = 0.0f;
            out[5 * DET + r] = 0.0f;
        }
    }
    if ((int)blockIdx.x * 256 >= K) return;   // block-uniform

    // gather compact key array from per-class slots
    #pragma unroll 1
    for (int c = 0; c < CF; ++c) {
        const int b = base[c], n = base[c + 1] - b;
        for (int j = tid; j < n; j += 256) keysh[b + j] = gkeys[c * DET + j];
    }
    const int Kpad = (K + 15) & ~15;          // <= NCAND always
    for (int t = K + tid; t < Kpad; t += 256) keysh[t] = 0ull;
    __syncthreads();

    const int g = blockIdx.x * 256 + tid;
    if (g >= K) return;
    const unsigned long long my = keysh[g];

    const ulonglong2* kp = (const ulonglong2*)keysh;
    const int nb2 = Kpad >> 1;                // multiple of 8
    int rank = 0;
    for (int j = 0; j < nb2; j += 8) {
        ulonglong2 kk[8];
        #pragma unroll
        for (int u = 0; u < 8; ++u) kk[u] = kp[j + u];
        #pragma unroll
        for (int u = 0; u < 8; ++u) {
            rank += (kk[u].x > my) ? 1 : 0;
            rank += (kk[u].y > my) ? 1 : 0;
        }
    }

    if (rank < DET) {
        const float sc  = __uint_as_float((unsigned)(my >> 16));
        const int  slot = 65535 - (int)(my & 0xFFFFull);
        const float4 b = gboxes[slot];
        out[rank * 4 + 0] = b.x;
        out[rank * 4 + 1] = b.y;
        out[rank * 4 + 2] = b.z;
        out[rank * 4 + 3] = b.w;
        out[4 * DET + rank] = sc;
        out[5 * DET + rank] = (float)(slot / DET + 1);
    }
}

// ---------------------------------------------------------------------------
extern "C" void kernel_launch(void* const* d_in, const int* in_sizes, int n_in,
                              void* d_out, int out_size, void* d_ws, size_t ws_size,
                              hipStream_t stream) {
    (void)in_sizes; (void)n_in; (void)out_size; (void)ws_size;

    const float* class_logits   = (const float*)d_in[0];  // [NP, NC]
    const float* box_regression = (const float*)d_in[1];  // [NP, 4*NC]
    const float* proposals      = (const float*)d_in[2];  // [NP, 4]
    float* out = (float*)d_out;                           // 600 floats

    // Workspace layout (float units; 16B-aligned)
    float* ws       = (float*)d_ws;
    float4* gboxes  = (float4*)ws;                                  // NCAND
    unsigned long long* gkeys =
        (unsigned long long*)(ws + (size_t)NCAND * 4);              // NCAND
    int* gcnt       = (int*)(ws + (size_t)NCAND * 4 + (size_t)NCAND * 2);  // CF

    class_nms_fused<<<dim3(CF), dim3(256), 0, stream>>>(
        class_logits, box_regression, proposals, gkeys, gboxes, gcnt);

    topk_rank_kernel<<<dim3((NCAND + 255) / 256), dim3(256), 0, stream>>>(
        gkeys, gboxes, gcnt, out);
}

// Round 2
// 108.607 us; speedup vs baseline: 1.3554x; 1.3554x over previous
//
#include <hip/hip_runtime.h>
#include <math.h>

#define NP 1024          // proposals
#define NC 81            // classes incl background
#define CF 80            // foreground classes
#define DET 100          // detections per image
#define SCORE_THRESH 0.05f
#define NMS_THRESH 0.5f
#define BBOX_CLIP 4.135166556742356f   // log(1000/16)
#define IMG_W 1333
#define IMG_H 800

#define NCAND (CF * DET)   // 8000 fixed per-class slots

// ---------------------------------------------------------------------------
// Kernel 1: per-proposal softmax scores (Round-0 verbatim — bit-exact proven).
// One wave per proposal, 4/block. Block 0 zeroes d_out and the done counter.
// ---------------------------------------------------------------------------
__global__ __launch_bounds__(256) void
softmax_kernel(const float* __restrict__ logits,
               float* __restrict__ scores_fg,
               float* __restrict__ out,
               int* __restrict__ done) {
    if (blockIdx.x == 0) {
        for (int t = threadIdx.x; t < 6 * DET; t += 256) out[t] = 0.0f;
        if (threadIdx.x == 0) *done = 0;
    }

    const int wave = threadIdx.x >> 6;
    const int lane = threadIdx.x & 63;
    const int i = blockIdx.x * 4 + wave;          // proposal index

    const float x0 = logits[i * NC + lane];
    const float x1 = (lane < NC - 64) ? logits[i * NC + 64 + lane] : -INFINITY;

    float m = fmaxf(x0, x1);
    for (int off = 32; off > 0; off >>= 1) m = fmaxf(m, __shfl_xor(m, off));

    const float e0 = expf(x0 - m);
    const float e1 = (lane < NC - 64) ? expf(x1 - m) : 0.0f;
    float sum = e0 + e1;
    for (int off = 32; off > 0; off >>= 1) sum += __shfl_xor(sum, off);

    if (lane >= 1) scores_fg[(lane - 1) * NP + i] = e0 / sum;
    if (lane < NC - 64) scores_fg[(64 + lane - 1) * NP + i] = e1 / sum;
}

// ---------------------------------------------------------------------------
// Kernel 2: per-class NMS (proven fast/slow paths) + in-kernel topk.
// 80 blocks x 256 threads, LDS ~65KB -> >=2 blocks/CU capacity: all 80 blocks
// co-resident (80 << 256 CUs), so the done-counter barrier cannot deadlock.
// Chain: block writes gkeys/gboxes/gcnt -> release fetch_add(done) [agent
// scope: wbl2 on release, inv on acquire handles cross-XCD L2 non-coherence]
// -> tid0 spins to 80 -> all blocks gather keys (flat parallel, no serial
// chains) -> block b ranks candidates [b*100, b*100+100) with wave-uniform
// early exit (exact for rank<DET winners).
// ---------------------------------------------------------------------------
__global__ __launch_bounds__(256) void
nms_topk_kernel(const float* __restrict__ scores_fg,
                const float* __restrict__ rel,
                const float* __restrict__ props,
                unsigned long long* __restrict__ gkeys,
                float4* __restrict__ gboxes,
                int* __restrict__ gcnt,
                int* __restrict__ done,
                float* __restrict__ out) {
    const int cls = blockIdx.x;   // fg class (reference class = cls+1)
    const int tid = threadIdx.x;  // 0..255

    // phase-B arrays union with phase-T keysh (phase-B data dead by then)
    __shared__ __align__(16) unsigned char smem[NCAND * 8];   // 64000 B
    __shared__ int cntSh;
    __shared__ int keptRank[DET];
    __shared__ int keptCnt;
    __shared__ int cshare[CF];
    __shared__ int cbase[CF + 1];

    unsigned long long* key = (unsigned long long*)smem;             // 8 KB
    float4* vbox = (float4*)(smem + 8192);                           // 16 KB
    unsigned char* supp = (unsigned char*)(smem + 8192 + 16384);     // 1 KB

    if (tid == 0) cntSh = 0;
    __syncthreads();

    // threshold compaction: 1024 scores, 1 float4 per thread
    {
        const float4* srow = (const float4*)(scores_fg + cls * NP);
        const float4 v = srow[tid];
        const int id0 = tid * 4;
        if (v.x > SCORE_THRESH) { int p = atomicAdd(&cntSh, 1); key[p] = ((unsigned long long)__float_as_uint(v.x) << 16) | (unsigned long long)(1023 - (id0 + 0)); }
        if (v.y > SCORE_THRESH) { int p = atomicAdd(&cntSh, 1); key[p] = ((unsigned long long)__float_as_uint(v.y) << 16) | (unsigned long long)(1023 - (id0 + 1)); }
        if (v.z > SCORE_THRESH) { int p = atomicAdd(&cntSh, 1); key[p] = ((unsigned long long)__float_as_uint(v.z) << 16) | (unsigned long long)(1023 - (id0 + 2)); }
        if (v.w > SCORE_THRESH) { int p = atomicAdd(&cntSh, 1); key[p] = ((unsigned long long)__float_as_uint(v.w) << 16) | (unsigned long long)(1023 - (id0 + 3)); }
    }
    __syncthreads();
    const int cnt = cntSh;

    if (cnt == 0) {
        if (tid == 0) gcnt[cls] = 0;
    } else if (cnt <= 64) {
        // ================== FAST PATH: cnt<=64 (wave 0 active) ==============
        unsigned long long my = 0ull;
        int rk = 0;
        if (tid < cnt) {
            my = key[tid];
            for (int i = 0; i < cnt; ++i) rk += (key[i] > my) ? 1 : 0;
        }
        __syncthreads();
        if (tid < cnt) key[rk] = my;
        __syncthreads();

        if (tid < cnt) {
            const int id = 1023 - (int)(key[tid] & 0xFFFFull);
            const float4 p = ((const float4*)props)[id];
            const float w  = p.z - p.x + 1.0f;
            const float h  = p.w - p.y + 1.0f;
            const float cx = p.x + 0.5f * w;
            const float cy = p.y + 0.5f * h;

            const float4 r = ((const float4*)rel)[id * NC + (cls + 1)];
            const float dx = r.x / 10.0f;
            const float dy = r.y / 10.0f;
            const float dw = fminf(r.z / 5.0f, BBOX_CLIP);
            const float dh = fminf(r.w / 5.0f, BBOX_CLIP);

            const float pcx = dx * w + cx;
            const float pcy = dy * h + cy;
            const float pw  = expf(dw) * w;
            const float ph  = expf(dh) * h;

            float bx1 = pcx - 0.5f * pw;
            float by1 = pcy - 0.5f * ph;
            float bx2 = pcx + 0.5f * pw - 1.0f;
            float by2 = pcy + 0.5f * ph - 1.0f;

            bx1 = fminf(fmaxf(bx1, 0.0f), (float)(IMG_W - 1));
            bx2 = fminf(fmaxf(bx2, 0.0f), (float)(IMG_W - 1));
            by1 = fminf(fmaxf(by1, 0.0f), (float)(IMG_H - 1));
            by2 = fminf(fmaxf(by2, 0.0f), (float)(IMG_H - 1));

            vbox[tid] = make_float4(bx1, by1, bx2, by2);
        }
        __syncthreads();

        unsigned long long mymask = 0ull;
        if (tid < cnt) {
            const float4 bj = vbox[tid];
            const float areaj = (bj.z - bj.x + 1.0f) * (bj.w - bj.y + 1.0f);
            for (int i = 0; i < tid; ++i) {
                const float4 bi = vbox[i];            // LDS broadcast
                const float areai = (bi.z - bi.x + 1.0f) * (bi.w - bi.y + 1.0f);
                const float ltx = fmaxf(bi.x, bj.x);
                const float lty = fmaxf(bi.y, bj.y);
                const float rbx = fminf(bi.z, bj.z);
                const float rby = fminf(bi.w, bj.w);
                const float wq = fmaxf(rbx - ltx + 1.0f, 0.0f);
                const float hq = fmaxf(rby - lty + 1.0f, 0.0f);
                const float inter = wq * hq;
                const float iou = inter / (areai + areaj - inter);
                if (iou > NMS_THRESH) mymask |= (1ull << i);
            }
        }
        // resolve in every wave; only wave-0 results are used (tid<cnt<=64)
        unsigned long long suppbits = 0ull;
        for (int i = 0; i < cnt; ++i) {
            if (!((suppbits >> i) & 1ull)) {
                const unsigned long long vote = __ballot((mymask >> i) & 1ull);
                suppbits |= vote;
            }
        }
        unsigned long long kb = ~suppbits;
        if (cnt < 64) kb &= ((1ull << cnt) - 1ull);
        const int c2 = __popcll(kb);

        if (tid == 0) gcnt[cls] = c2;
        if (tid < cnt && !((suppbits >> tid) & 1ull)) {
            const int kr = __popcll(kb & ((1ull << tid) - 1ull));
            const int slot = cls * DET + kr;
            const unsigned int bits = (unsigned int)(key[tid] >> 16);
            gkeys[slot] = ((unsigned long long)bits << 16) |
                          (unsigned long long)(65535 - slot);
            gboxes[slot] = vbox[tid];
        }
    } else {
        // ===================== SLOW PATH: cnt>64 ============================
        int msz = 1;
        while (msz < cnt) msz <<= 1;
        for (int t = cnt + tid; t < msz; t += 256) key[t] = 0ull;
        __syncthreads();

        for (int k = 2; k <= msz; k <<= 1) {
            for (int jj = k >> 1; jj > 0; jj >>= 1) {
                for (int t = tid; t < msz; t += 256) {
                    const int ixj = t ^ jj;
                    if (ixj > t) {
                        const unsigned long long a = key[t], b = key[ixj];
                        const bool tAfter = (a < b);
                        const bool dirAsc = ((t & k) == 0);
                        if (dirAsc ? tAfter : !tAfter) { key[t] = b; key[ixj] = a; }
                    }
                }
                __syncthreads();
            }
        }

        for (int t = tid; t < cnt; t += 256) {
            const int id = 1023 - (int)(key[t] & 0xFFFFull);
            const float4 p = ((const float4*)props)[id];
            const float w  = p.z - p.x + 1.0f;
            const float h  = p.w - p.y + 1.0f;
            const float cx = p.x + 0.5f * w;
            const float cy = p.y + 0.5f * h;

            const float4 r = ((const float4*)rel)[id * NC + (cls + 1)];
            const float dx = r.x / 10.0f;
            const float dy = r.y / 10.0f;
            const float dw = fminf(r.z / 5.0f, BBOX_CLIP);
            const float dh = fminf(r.w / 5.0f, BBOX_CLIP);

            const float pcx = dx * w + cx;
            const float pcy = dy * h + cy;
            const float pw  = expf(dw) * w;
            const float ph  = expf(dh) * h;

            float bx1 = pcx - 0.5f * pw;
            float by1 = pcy - 0.5f * ph;
            float bx2 = pcx + 0.5f * pw - 1.0f;
            float by2 = pcy + 0.5f * ph - 1.0f;

            bx1 = fminf(fmaxf(bx1, 0.0f), (float)(IMG_W - 1));
            bx2 = fminf(fmaxf(bx2, 0.0f), (float)(IMG_W - 1));
            by1 = fminf(fmaxf(by1, 0.0f), (float)(IMG_H - 1));
            by2 = fminf(fmaxf(by2, 0.0f), (float)(IMG_H - 1));

            vbox[t] = make_float4(bx1, by1, bx2, by2);
            supp[t] = 0;
        }
        __syncthreads();

        for (int i = 0; i < cnt; ++i) {
            if (!supp[i]) {
                const float4 bi = vbox[i];
                const float areai = (bi.z - bi.x + 1.0f) * (bi.w - bi.y + 1.0f);
                for (int t = i + 1 + tid; t < cnt; t += 256) {
                    const float4 bj = vbox[t];
                    const float areaj = (bj.z - bj.x + 1.0f) * (bj.w - bj.y + 1.0f);
                    const float ltx = fmaxf(bi.x, bj.x);
                    const float lty = fmaxf(bi.y, bj.y);
                    const float rbx = fminf(bi.z, bj.z);
                    const float rby = fminf(bi.w, bj.w);
                    const float wq = fmaxf(rbx - ltx + 1.0f, 0.0f);
                    const float hq = fmaxf(rby - lty + 1.0f, 0.0f);
                    const float inter = wq * hq;
                    const float iou = inter / (areai + areaj - inter);
                    if (iou > NMS_THRESH) supp[t] = 1;
                }
            }
            __syncthreads();
        }

        if (tid == 0) {
            int c2 = 0;
            for (int r = 0; r < cnt && c2 < DET; ++r)
                if (!supp[r]) keptRank[c2++] = r;
            keptCnt = c2;
            gcnt[cls] = c2;
        }
        __syncthreads();

        const int kc = keptCnt;
        for (int t = tid; t < kc; t += 256) {
            const int r = keptRank[t];
            const int slot = cls * DET + t;
            const unsigned int bits = (unsigned int)(key[r] >> 16);
            gkeys[slot] = ((unsigned long long)bits << 16) |
                          (unsigned long long)(65535 - slot);
            gboxes[slot] = vbox[r];
        }
    }

    // ---------------- device-scope barrier (all 80 blocks) ------------------
    __syncthreads();   // all block writes drained (waitcnt before s_barrier)
    if (tid == 0) {
        __hip_atomic_fetch_add(done, 1, __ATOMIC_ACQ_REL,
                               __HIP_MEMORY_SCOPE_AGENT);
        while (__hip_atomic_load(done, __ATOMIC_ACQUIRE,
                                 __HIP_MEMORY_SCOPE_AGENT) < CF)
            __builtin_amdgcn_s_sleep(8);
    }
    __syncthreads();

    // ---------------- Phase T: cooperative topk -----------------------------
    // counts + exclusive prefix (thread c sums c entries; cheap, parallel)
    if (tid < CF) cshare[tid] = gcnt[tid];
    __syncthreads();
    if (tid <= CF) {
        int acc = 0;
        for (int i = 0; i < tid; ++i) acc += cshare[i];
        cbase[tid] = acc;
    }
    __syncthreads();
    const int K = cbase[CF];

    // flat parallel gather: 32 fully independent iterations, no serial chains
    unsigned long long* keysh = (unsigned long long*)smem;   // reuses phase-B
    for (int g = tid; g < NCAND; g += 256) {
        const int c = g / DET;          // const-div -> magic mul
        const int j = g - c * DET;
        if (j < cshare[c]) keysh[cbase[c] + j] = gkeys[g];
    }
    const int Kpad = (K + 15) & ~15;
    for (int t = K + tid; t < Kpad; t += 256) keysh[t] = 0ull;
    __syncthreads();

    // block b ranks candidates [b*DET, b*DET+DET) of the compacted array
    const int g2 = cls * DET + tid;
    const bool active = (tid < DET) && (g2 < K);
    const unsigned long long my = active ? keysh[g2] : 0ull;
    int rank = active ? 0 : DET;        // inactive lanes never block early-exit

    const ulonglong2* kp = (const ulonglong2*)keysh;
    const int nb2 = Kpad >> 1;          // multiple of 8
    for (int j0 = 0; j0 < nb2; j0 += 8) {
        ulonglong2 kk[8];
        #pragma unroll
        for (int u = 0; u < 8; ++u) kk[u] = kp[j0 + u];  // broadcast reads
        #pragma unroll
        for (int u = 0; u < 8; ++u) {
            rank += (kk[u].x > my) ? 1 : 0;
            rank += (kk[u].y > my) ? 1 : 0;
        }
        // wave-uniform early exit: exact for winners (they keep rank<DET and
        // scan to completion); losers' partial rank is monotone >=DET.
        if (__all(rank >= DET)) break;
    }

    if (active && rank < DET) {
        const float sc  = __uint_as_float((unsigned)(my >> 16));
        const int  slot = 65535 - (int)(my & 0xFFFFull);
        const float4 b = gboxes[slot];
        out[rank * 4 + 0] = b.x;
        out[rank * 4 + 1] = b.y;
        out[rank * 4 + 2] = b.z;
        out[rank * 4 + 3] = b.w;
        out[4 * DET + rank] = sc;                       // score (>0 always)
        out[5 * DET + rank] = (float)(slot / DET + 1);  // label
    }
}

// ---------------------------------------------------------------------------
extern "C" void kernel_launch(void* const* d_in, const int* in_sizes, int n_in,
                              void* d_out, int out_size, void* d_ws, size_t ws_size,
                              hipStream_t stream) {
    (void)in_sizes; (void)n_in; (void)out_size; (void)ws_size;

    const float* class_logits   = (const float*)d_in[0];  // [NP, NC]
    const float* box_regression = (const float*)d_in[1];  // [NP, 4*NC]
    const float* proposals      = (const float*)d_in[2];  // [NP, 4]
    float* out = (float*)d_out;                           // 600 floats

    // Workspace layout (float units; all offsets 16B-aligned)
    float* ws        = (float*)d_ws;
    float* gboxes_f  = ws;                                    // NCAND*4 = 32000
    float* gkeys_f   = gboxes_f + (size_t)NCAND * 4;          // NCAND*2 = 16000
    float* scores_fg = gkeys_f + (size_t)NCAND * 2;           // CF*NP   = 81920
    int*   gcnt      = (int*)(scores_fg + (size_t)CF * NP);   // CF ints
    int*   done      = gcnt + CF;                             // 1 int

    unsigned long long* gkeys = (unsigned long long*)gkeys_f;
    float4* gboxes = (float4*)gboxes_f;

    softmax_kernel<<<dim3(NP / 4), dim3(256), 0, stream>>>(
        class_logits, scores_fg, out, done);

    nms_topk_kernel<<<dim3(CF), dim3(256), 0, stream>>>(
        scores_fg, box_regression, proposals, gkeys, gboxes, gcnt, done, out);
}

// Round 3
// 87.049 us; speedup vs baseline: 1.6911x; 1.2477x over previous
//
#include <hip/hip_runtime.h>
#include <math.h>

#define NP 1024          // proposals
#define NC 81            // classes incl background
#define CF 80            // foreground classes
#define DET 100          // detections per image
#define SCORE_THRESH 0.05f
#define NMS_THRESH 0.5f
#define BBOX_CLIP 4.135166556742356f   // log(1000/16)
#define IMG_W 1333
#define IMG_H 800

#define NCAND (CF * DET)   // 8000 fixed per-class slots

// histogram-select parameters: bucket = clamp((key>>29) - HOFF, 0, HB-1).
// key>>29 == score_bits>>13; score in (0.05, 1] -> raw range [125542,130048].
// Map is monotone non-decreasing in key => selection stays EXACT (same-bucket
// ties are resolved on the full unique 64-bit key).
#define HB   4608          // 256 chunks x 18
#define CH   18
#define HOFF 125542

__device__ __forceinline__ int bucketOf(unsigned long long k) {
    int b = (int)(unsigned)(k >> 29) - HOFF;
    b = b < 0 ? 0 : b;
    b = b > HB - 1 ? HB - 1 : b;
    return b;
}

// ---------------------------------------------------------------------------
// Kernel 1: per-proposal softmax scores (Round-0 verbatim — bit-exact proven).
// One wave per proposal, 4/block. Block 0 zeroes d_out and the done counter.
// ---------------------------------------------------------------------------
__global__ __launch_bounds__(256) void
softmax_kernel(const float* __restrict__ logits,
               float* __restrict__ scores_fg,
               float* __restrict__ out,
               int* __restrict__ done) {
    if (blockIdx.x == 0) {
        for (int t = threadIdx.x; t < 6 * DET; t += 256) out[t] = 0.0f;
        if (threadIdx.x == 0) *done = 0;
    }

    const int wave = threadIdx.x >> 6;
    const int lane = threadIdx.x & 63;
    const int i = blockIdx.x * 4 + wave;          // proposal index

    const float x0 = logits[i * NC + lane];
    const float x1 = (lane < NC - 64) ? logits[i * NC + 64 + lane] : -INFINITY;

    float m = fmaxf(x0, x1);
    for (int off = 32; off > 0; off >>= 1) m = fmaxf(m, __shfl_xor(m, off));

    const float e0 = expf(x0 - m);
    const float e1 = (lane < NC - 64) ? expf(x1 - m) : 0.0f;
    float sum = e0 + e1;
    for (int off = 32; off > 0; off >>= 1) sum += __shfl_xor(sum, off);

    if (lane >= 1) scores_fg[(lane - 1) * NP + i] = e0 / sum;
    if (lane < NC - 64) scores_fg[(64 + lane - 1) * NP + i] = e1 / sum;
}

// ---------------------------------------------------------------------------
// Kernel 2: per-class NMS (proven fast/slow paths) + LAST-BLOCK topk.
// 80 blocks x 256 threads. After writing its class results, each block does
// ONE release fetch_add(done); blocks 1..79 to finish EXIT immediately (no
// spinning, no co-residency requirement, no deadlock possible). The 80th
// arrival's ACQUIRE pairs with all earlier RELEASEs -> it sees every class's
// gkeys/gboxes/gcnt, and alone runs the histogram-select topk (~5 us).
// ---------------------------------------------------------------------------
__global__ __launch_bounds__(256) void
nms_topk_kernel(const float* __restrict__ scores_fg,
                const float* __restrict__ rel,
                const float* __restrict__ props,
                unsigned long long* __restrict__ gkeys,
                float4* __restrict__ gboxes,
                int* __restrict__ gcnt,
                int* __restrict__ done,
                float* __restrict__ out) {
    const int cls = blockIdx.x;   // fg class (reference class = cls+1)
    const int tid = threadIdx.x;  // 0..255

    // phase-B arrays union with phase-T keysh (phase-B data dead by then)
    __shared__ __align__(16) unsigned char smem[NCAND * 8];   // 64000 B
    __shared__ int hist[HB];          // 18 KB (phase T)
    __shared__ int qidx[NCAND];       // 32 KB (phase T qualifier list)
    __shared__ int csum[256];
    __shared__ int ccar[256];
    __shared__ int cntSh;
    __shared__ int keptRank[DET];
    __shared__ int keptCnt;
    __shared__ int cshare[CF];
    __shared__ int cbase[CF + 1];
    __shared__ int lastSh;
    __shared__ int qnSh;

    unsigned long long* key = (unsigned long long*)smem;             // 8 KB
    float4* vbox = (float4*)(smem + 8192);                           // 16 KB
    unsigned char* supp = (unsigned char*)(smem + 8192 + 16384);     // 1 KB

    if (tid == 0) cntSh = 0;
    __syncthreads();

    // threshold compaction: 1024 scores, 1 float4 per thread
    {
        const float4* srow = (const float4*)(scores_fg + cls * NP);
        const float4 v = srow[tid];
        const int id0 = tid * 4;
        if (v.x > SCORE_THRESH) { int p = atomicAdd(&cntSh, 1); key[p] = ((unsigned long long)__float_as_uint(v.x) << 16) | (unsigned long long)(1023 - (id0 + 0)); }
        if (v.y > SCORE_THRESH) { int p = atomicAdd(&cntSh, 1); key[p] = ((unsigned long long)__float_as_uint(v.y) << 16) | (unsigned long long)(1023 - (id0 + 1)); }
        if (v.z > SCORE_THRESH) { int p = atomicAdd(&cntSh, 1); key[p] = ((unsigned long long)__float_as_uint(v.z) << 16) | (unsigned long long)(1023 - (id0 + 2)); }
        if (v.w > SCORE_THRESH) { int p = atomicAdd(&cntSh, 1); key[p] = ((unsigned long long)__float_as_uint(v.w) << 16) | (unsigned long long)(1023 - (id0 + 3)); }
    }
    __syncthreads();
    const int cnt = cntSh;

    if (cnt == 0) {
        if (tid == 0) gcnt[cls] = 0;
    } else if (cnt <= 64) {
        // ================== FAST PATH: cnt<=64 (wave 0 active) ==============
        unsigned long long my = 0ull;
        int rk = 0;
        if (tid < cnt) {
            my = key[tid];
            for (int i = 0; i < cnt; ++i) rk += (key[i] > my) ? 1 : 0;
        }
        __syncthreads();
        if (tid < cnt) key[rk] = my;
        __syncthreads();

        if (tid < cnt) {
            const int id = 1023 - (int)(key[tid] & 0xFFFFull);
            const float4 p = ((const float4*)props)[id];
            const float w  = p.z - p.x + 1.0f;
            const float h  = p.w - p.y + 1.0f;
            const float cx = p.x + 0.5f * w;
            const float cy = p.y + 0.5f * h;

            const float4 r = ((const float4*)rel)[id * NC + (cls + 1)];
            const float dx = r.x / 10.0f;
            const float dy = r.y / 10.0f;
            const float dw = fminf(r.z / 5.0f, BBOX_CLIP);
            const float dh = fminf(r.w / 5.0f, BBOX_CLIP);

            const float pcx = dx * w + cx;
            const float pcy = dy * h + cy;
            const float pw  = expf(dw) * w;
            const float ph  = expf(dh) * h;

            float bx1 = pcx - 0.5f * pw;
            float by1 = pcy - 0.5f * ph;
            float bx2 = pcx + 0.5f * pw - 1.0f;
            float by2 = pcy + 0.5f * ph - 1.0f;

            bx1 = fminf(fmaxf(bx1, 0.0f), (float)(IMG_W - 1));
            bx2 = fminf(fmaxf(bx2, 0.0f), (float)(IMG_W - 1));
            by1 = fminf(fmaxf(by1, 0.0f), (float)(IMG_H - 1));
            by2 = fminf(fmaxf(by2, 0.0f), (float)(IMG_H - 1));

            vbox[tid] = make_float4(bx1, by1, bx2, by2);
        }
        __syncthreads();

        unsigned long long mymask = 0ull;
        if (tid < cnt) {
            const float4 bj = vbox[tid];
            const float areaj = (bj.z - bj.x + 1.0f) * (bj.w - bj.y + 1.0f);
            for (int i = 0; i < tid; ++i) {
                const float4 bi = vbox[i];            // LDS broadcast
                const float areai = (bi.z - bi.x + 1.0f) * (bi.w - bi.y + 1.0f);
                const float ltx = fmaxf(bi.x, bj.x);
                const float lty = fmaxf(bi.y, bj.y);
                const float rbx = fminf(bi.z, bj.z);
                const float rby = fminf(bi.w, bj.w);
                const float wq = fmaxf(rbx - ltx + 1.0f, 0.0f);
                const float hq = fmaxf(rby - lty + 1.0f, 0.0f);
                const float inter = wq * hq;
                const float iou = inter / (areai + areaj - inter);
                if (iou > NMS_THRESH) mymask |= (1ull << i);
            }
        }
        // resolve in every wave; only wave-0 results are used (tid<cnt<=64)
        unsigned long long suppbits = 0ull;
        for (int i = 0; i < cnt; ++i) {
            if (!((suppbits >> i) & 1ull)) {
                const unsigned long long vote = __ballot((mymask >> i) & 1ull);
                suppbits |= vote;
            }
        }
        unsigned long long kb = ~suppbits;
        if (cnt < 64) kb &= ((1ull << cnt) - 1ull);
        const int c2 = __popcll(kb);

        if (tid == 0) gcnt[cls] = c2;
        if (tid < cnt && !((suppbits >> tid) & 1ull)) {
            const int kr = __popcll(kb & ((1ull << tid) - 1ull));
            const int slot = cls * DET + kr;
            const unsigned int bits = (unsigned int)(key[tid] >> 16);
            gkeys[slot] = ((unsigned long long)bits << 16) |
                          (unsigned long long)(65535 - slot);
            gboxes[slot] = vbox[tid];
        }
    } else {
        // ===================== SLOW PATH: cnt>64 ============================
        int msz = 1;
        while (msz < cnt) msz <<= 1;
        for (int t = cnt + tid; t < msz; t += 256) key[t] = 0ull;
        __syncthreads();

        for (int k = 2; k <= msz; k <<= 1) {
            for (int jj = k >> 1; jj > 0; jj >>= 1) {
                for (int t = tid; t < msz; t += 256) {
                    const int ixj = t ^ jj;
                    if (ixj > t) {
                        const unsigned long long a = key[t], b = key[ixj];
                        const bool tAfter = (a < b);
                        const bool dirAsc = ((t & k) == 0);
                        if (dirAsc ? tAfter : !tAfter) { key[t] = b; key[ixj] = a; }
                    }
                }
                __syncthreads();
            }
        }

        for (int t = tid; t < cnt; t += 256) {
            const int id = 1023 - (int)(key[t] & 0xFFFFull);
            const float4 p = ((const float4*)props)[id];
            const float w  = p.z - p.x + 1.0f;
            const float h  = p.w - p.y + 1.0f;
            const float cx = p.x + 0.5f * w;
            const float cy = p.y + 0.5f * h;

            const float4 r = ((const float4*)rel)[id * NC + (cls + 1)];
            const float dx = r.x / 10.0f;
            const float dy = r.y / 10.0f;
            const float dw = fminf(r.z / 5.0f, BBOX_CLIP);
            const float dh = fminf(r.w / 5.0f, BBOX_CLIP);

            const float pcx = dx * w + cx;
            const float pcy = dy * h + cy;
            const float pw  = expf(dw) * w;
            const float ph  = expf(dh) * h;

            float bx1 = pcx - 0.5f * pw;
            float by1 = pcy - 0.5f * ph;
            float bx2 = pcx + 0.5f * pw - 1.0f;
            float by2 = pcy + 0.5f * ph - 1.0f;

            bx1 = fminf(fmaxf(bx1, 0.0f), (float)(IMG_W - 1));
            bx2 = fminf(fmaxf(bx2, 0.0f), (float)(IMG_W - 1));
            by1 = fminf(fmaxf(by1, 0.0f), (float)(IMG_H - 1));
            by2 = fminf(fmaxf(by2, 0.0f), (float)(IMG_H - 1));

            vbox[t] = make_float4(bx1, by1, bx2, by2);
            supp[t] = 0;
        }
        __syncthreads();

        for (int i = 0; i < cnt; ++i) {
            if (!supp[i]) {
                const float4 bi = vbox[i];
                const float areai = (bi.z - bi.x + 1.0f) * (bi.w - bi.y + 1.0f);
                for (int t = i + 1 + tid; t < cnt; t += 256) {
                    const float4 bj = vbox[t];
                    const float areaj = (bj.z - bj.x + 1.0f) * (bj.w - bj.y + 1.0f);
                    const float ltx = fmaxf(bi.x, bj.x);
                    const float lty = fmaxf(bi.y, bj.y);
                    const float rbx = fminf(bi.z, bj.z);
                    const float rby = fminf(bi.w, bj.w);
                    const float wq = fmaxf(rbx - ltx + 1.0f, 0.0f);
                    const float hq = fmaxf(rby - lty + 1.0f, 0.0f);
                    const float inter = wq * hq;
                    const float iou = inter / (areai + areaj - inter);
                    if (iou > NMS_THRESH) supp[t] = 1;
                }
            }
            __syncthreads();
        }

        if (tid == 0) {
            int c2 = 0;
            for (int r = 0; r < cnt && c2 < DET; ++r)
                if (!supp[r]) keptRank[c2++] = r;
            keptCnt = c2;
            gcnt[cls] = c2;
        }
        __syncthreads();

        const int kc = keptCnt;
        for (int t = tid; t < kc; t += 256) {
            const int r = keptRank[t];
            const int slot = cls * DET + t;
            const unsigned int bits = (unsigned int)(key[r] >> 16);
            gkeys[slot] = ((unsigned long long)bits << 16) |
                          (unsigned long long)(65535 - slot);
            gboxes[slot] = vbox[r];
        }
    }

    // ---------------- last-block election (NO spinning) ---------------------
    __syncthreads();   // all this block's writes drained before the release
    if (tid == 0) {
        const int prev = __hip_atomic_fetch_add(done, 1, __ATOMIC_ACQ_REL,
                                                __HIP_MEMORY_SCOPE_AGENT);
        lastSh = (prev == CF - 1);
    }
    __syncthreads();
    if (!lastSh) return;   // 79 blocks retire immediately

    // ---------------- Phase T: single-block histogram-select topk -----------
    if (tid < CF) cshare[tid] = gcnt[tid];
    __syncthreads();
    if (tid <= CF) {
        int acc = 0;
        for (int i = 0; i < tid; ++i) acc += cshare[i];
        cbase[tid] = acc;
    }
    __syncthreads();
    const int K = cbase[CF];

    // flat parallel gather of the compacted key array
    unsigned long long* keysh = (unsigned long long*)smem;   // reuses phase-B
    for (int g = tid; g < NCAND; g += 256) {
        const int c = g / DET;          // const-div -> magic mul
        const int j = g - c * DET;
        if (j < cshare[c]) keysh[cbase[c] + j] = gkeys[g];
    }
    for (int t = tid; t < HB; t += 256) hist[t] = 0;
    __syncthreads();

    // histogram over monotone score-bit buckets
    for (int t = tid; t < K; t += 256) atomicAdd(&hist[bucketOf(keysh[t])], 1);
    __syncthreads();

    // inclusive suffix counts: hist[b] := #{keys with bucket >= b}
    {
        int ssum = 0;
        const int b0 = tid * CH;
        for (int u = 0; u < CH; ++u) ssum += hist[b0 + u];
        csum[tid] = ssum;
    }
    __syncthreads();
    {
        int c = 0;
        for (int i = tid + 1; i < 256; ++i) c += csum[i];
        ccar[tid] = c;
    }
    __syncthreads();
    {
        int acc = ccar[tid];
        const int b0 = tid * CH;
        for (int u = CH - 1; u >= 0; --u) { acc += hist[b0 + u]; hist[b0 + u] = acc; }
    }
    if (tid == 0) qnSh = 0;
    __syncthreads();

    // qualifiers: candidates whose strictly-above-bucket count < DET.
    // (every final rank<DET winner qualifies: rank >= hist[b+1])
    for (int t = tid; t < K; t += 256) {
        const int b = bucketOf(keysh[t]);
        const int above = (b + 1 < HB) ? hist[b + 1] : 0;
        if (above < DET) qidx[atomicAdd(&qnSh, 1)] = t;
    }
    __syncthreads();
    const int qn = qnSh;

    // exact rank = above-bucket count + same-bucket greater keys (all of which
    // are themselves qualifiers, since qualification depends only on bucket)
    for (int q = tid; q < qn; q += 256) {
        const unsigned long long kq = keysh[qidx[q]];
        const int bq = bucketOf(kq);
        int rank = (bq + 1 < HB) ? hist[bq + 1] : 0;
        for (int p = 0; p < qn; ++p) {
            const unsigned long long kp2 = keysh[qidx[p]];   // LDS broadcast
            if (kp2 > kq && bucketOf(kp2) == bq) ++rank;
        }
        if (rank < DET) {
            const float sc  = __uint_as_float((unsigned)(kq >> 16));
            const int  slot = 65535 - (int)(kq & 0xFFFFull);
            const float4 bb = gboxes[slot];
            out[rank * 4 + 0] = bb.x;
            out[rank * 4 + 1] = bb.y;
            out[rank * 4 + 2] = bb.z;
            out[rank * 4 + 3] = bb.w;
            out[4 * DET + rank] = sc;                       // score (>0 always)
            out[5 * DET + rank] = (float)(slot / DET + 1);  // label
        }
    }
}

// ---------------------------------------------------------------------------
extern "C" void kernel_launch(void* const* d_in, const int* in_sizes, int n_in,
                              void* d_out, int out_size, void* d_ws, size_t ws_size,
                              hipStream_t stream) {
    (void)in_sizes; (void)n_in; (void)out_size; (void)ws_size;

    const float* class_logits   = (const float*)d_in[0];  // [NP, NC]
    const float* box_regression = (const float*)d_in[1];  // [NP, 4*NC]
    const float* proposals      = (const float*)d_in[2];  // [NP, 4]
    float* out = (float*)d_out;                           // 600 floats

    // Workspace layout (float units; all offsets 16B-aligned)
    float* ws        = (float*)d_ws;
    float* gboxes_f  = ws;                                    // NCAND*4 = 32000
    float* gkeys_f   = gboxes_f + (size_t)NCAND * 4;          // NCAND*2 = 16000
    float* scores_fg = gkeys_f + (size_t)NCAND * 2;           // CF*NP   = 81920
    int*   gcnt      = (int*)(scores_fg + (size_t)CF * NP);   // CF ints
    int*   done      = gcnt + CF;                             // 1 int

    unsigned long long* gkeys = (unsigned long long*)gkeys_f;
    float4* gboxes = (float4*)gboxes_f;

    softmax_kernel<<<dim3(NP / 4), dim3(256), 0, stream>>>(
        class_logits, scores_fg, out, done);

    nms_topk_kernel<<<dim3(CF), dim3(256), 0, stream>>>(
        scores_fg, box_regression, proposals, gkeys, gboxes, gcnt, done, out);
}

// Round 4
// 80.389 us; speedup vs baseline: 1.8312x; 1.0828x over previous
//
#include <hip/hip_runtime.h>
#include <math.h>

#define NP 1024          // proposals
#define NC 81            // classes incl background
#define CF 80            // foreground classes
#define DET 100          // detections per image
#define SCORE_THRESH 0.05f
#define NMS_THRESH 0.5f
#define BBOX_CLIP 4.135166556742356f   // log(1000/16)
#define IMG_W 1333
#define IMG_H 800

#define NCAND (CF * DET)   // 8000 fixed per-class slots
#define NT 512             // nms_topk block size (8 waves)

// histogram-select: bucket = clamp((key>>31) - HOFF, 0, HB-1).
// key>>31 == score_bits>>15; score in (0.05, 1] -> raw in [31385, 32512].
// Monotone non-decreasing in key => selection EXACT (same-bucket ties are
// resolved on the full unique 64-bit key; top clamp merges scores >~0.62,
// which only grows the qualifier set, never changes ranks).
#define HB   1024
#define HOFF 31385

__device__ __forceinline__ int bucketOf(unsigned long long k) {
    int b = (int)(unsigned)(k >> 31) - HOFF;
    b = b < 0 ? 0 : b;
    b = b > HB - 1 ? HB - 1 : b;
    return b;
}

// ---------------------------------------------------------------------------
// Kernel 1: per-proposal softmax scores (Round-0 verbatim — bit-exact proven).
// One wave per proposal, 4/block. Block 0 zeroes d_out and the done counter.
// ---------------------------------------------------------------------------
__global__ __launch_bounds__(256) void
softmax_kernel(const float* __restrict__ logits,
               float* __restrict__ scores_fg,
               float* __restrict__ out,
               int* __restrict__ done) {
    if (blockIdx.x == 0) {
        for (int t = threadIdx.x; t < 6 * DET; t += 256) out[t] = 0.0f;
        if (threadIdx.x == 0) *done = 0;
    }

    const int wave = threadIdx.x >> 6;
    const int lane = threadIdx.x & 63;
    const int i = blockIdx.x * 4 + wave;          // proposal index

    const float x0 = logits[i * NC + lane];
    const float x1 = (lane < NC - 64) ? logits[i * NC + 64 + lane] : -INFINITY;

    float m = fmaxf(x0, x1);
    for (int off = 32; off > 0; off >>= 1) m = fmaxf(m, __shfl_xor(m, off));

    const float e0 = expf(x0 - m);
    const float e1 = (lane < NC - 64) ? expf(x1 - m) : 0.0f;
    float sum = e0 + e1;
    for (int off = 32; off > 0; off >>= 1) sum += __shfl_xor(sum, off);

    if (lane >= 1) scores_fg[(lane - 1) * NP + i] = e0 / sum;
    if (lane < NC - 64) scores_fg[(64 + lane - 1) * NP + i] = e1 / sum;
}

// ---------------------------------------------------------------------------
// Kernel 2: per-class NMS (proven fast/slow paths, strides -> NT) + LAST-BLOCK
// topk. 80 blocks x 512 threads. Each block: class NMS -> one RELEASE
// fetch_add(done); 79 blocks exit immediately (no spin, no deadlock). The
// 80th arrival ACQUIREs (release-sequence pairing => sees all classes'
// gkeys/gboxes/gcnt) and alone runs histogram-select topk with 8 waves and
// shuffle-based suffix scan (no serial LDS dependency chains).
// ---------------------------------------------------------------------------
__global__ __launch_bounds__(NT) void
nms_topk_kernel(const float* __restrict__ scores_fg,
                const float* __restrict__ rel,
                const float* __restrict__ props,
                unsigned long long* __restrict__ gkeys,
                float4* __restrict__ gboxes,
                int* __restrict__ gcnt,
                int* __restrict__ done,
                float* __restrict__ out) {
    const int cls = blockIdx.x;   // fg class (reference class = cls+1)
    const int tid = threadIdx.x;  // 0..511

    // phase-B arrays union with phase-T keysh (phase-B data dead by then)
    __shared__ __align__(16) unsigned char smem[NCAND * 8];   // 64000 B
    __shared__ int hist[HB];          // 4 KB (phase T: counts, then suffix S)
    __shared__ int qidx[NCAND];       // 32 KB (phase T qualifier list)
    __shared__ int wtot[NT / 64];     // per-wave totals for suffix scan
    __shared__ int cntSh;
    __shared__ int keptRank[DET];
    __shared__ int keptCnt;
    __shared__ int cshare[CF];
    __shared__ int cbase[CF + 1];
    __shared__ int lastSh;
    __shared__ int qnSh;

    unsigned long long* key = (unsigned long long*)smem;             // 8 KB
    float4* vbox = (float4*)(smem + 8192);                           // 16 KB
    unsigned char* supp = (unsigned char*)(smem + 8192 + 16384);     // 1 KB

    if (tid == 0) cntSh = 0;
    __syncthreads();

    // threshold compaction: 1024 scores, 1 float4 per thread (tid<256)
    if (tid < NP / 4) {
        const float4* srow = (const float4*)(scores_fg + cls * NP);
        const float4 v = srow[tid];
        const int id0 = tid * 4;
        if (v.x > SCORE_THRESH) { int p = atomicAdd(&cntSh, 1); key[p] = ((unsigned long long)__float_as_uint(v.x) << 16) | (unsigned long long)(1023 - (id0 + 0)); }
        if (v.y > SCORE_THRESH) { int p = atomicAdd(&cntSh, 1); key[p] = ((unsigned long long)__float_as_uint(v.y) << 16) | (unsigned long long)(1023 - (id0 + 1)); }
        if (v.z > SCORE_THRESH) { int p = atomicAdd(&cntSh, 1); key[p] = ((unsigned long long)__float_as_uint(v.z) << 16) | (unsigned long long)(1023 - (id0 + 2)); }
        if (v.w > SCORE_THRESH) { int p = atomicAdd(&cntSh, 1); key[p] = ((unsigned long long)__float_as_uint(v.w) << 16) | (unsigned long long)(1023 - (id0 + 3)); }
    }
    __syncthreads();
    const int cnt = cntSh;

    if (cnt == 0) {
        if (tid == 0) gcnt[cls] = 0;
    } else if (cnt <= 64) {
        // ================== FAST PATH: cnt<=64 (wave 0 active) ==============
        unsigned long long my = 0ull;
        int rk = 0;
        if (tid < cnt) {
            my = key[tid];
            for (int i = 0; i < cnt; ++i) rk += (key[i] > my) ? 1 : 0;
        }
        __syncthreads();
        if (tid < cnt) key[rk] = my;
        __syncthreads();

        if (tid < cnt) {
            const int id = 1023 - (int)(key[tid] & 0xFFFFull);
            const float4 p = ((const float4*)props)[id];
            const float w  = p.z - p.x + 1.0f;
            const float h  = p.w - p.y + 1.0f;
            const float cx = p.x + 0.5f * w;
            const float cy = p.y + 0.5f * h;

            const float4 r = ((const float4*)rel)[id * NC + (cls + 1)];
            const float dx = r.x / 10.0f;
            const float dy = r.y / 10.0f;
            const float dw = fminf(r.z / 5.0f, BBOX_CLIP);
            const float dh = fminf(r.w / 5.0f, BBOX_CLIP);

            const float pcx = dx * w + cx;
            const float pcy = dy * h + cy;
            const float pw  = expf(dw) * w;
            const float ph  = expf(dh) * h;

            float bx1 = pcx - 0.5f * pw;
            float by1 = pcy - 0.5f * ph;
            float bx2 = pcx + 0.5f * pw - 1.0f;
            float by2 = pcy + 0.5f * ph - 1.0f;

            bx1 = fminf(fmaxf(bx1, 0.0f), (float)(IMG_W - 1));
            bx2 = fminf(fmaxf(bx2, 0.0f), (float)(IMG_W - 1));
            by1 = fminf(fmaxf(by1, 0.0f), (float)(IMG_H - 1));
            by2 = fminf(fmaxf(by2, 0.0f), (float)(IMG_H - 1));

            vbox[tid] = make_float4(bx1, by1, bx2, by2);
        }
        __syncthreads();

        unsigned long long mymask = 0ull;
        if (tid < cnt) {
            const float4 bj = vbox[tid];
            const float areaj = (bj.z - bj.x + 1.0f) * (bj.w - bj.y + 1.0f);
            for (int i = 0; i < tid; ++i) {
                const float4 bi = vbox[i];            // LDS broadcast
                const float areai = (bi.z - bi.x + 1.0f) * (bi.w - bi.y + 1.0f);
                const float ltx = fmaxf(bi.x, bj.x);
                const float lty = fmaxf(bi.y, bj.y);
                const float rbx = fminf(bi.z, bj.z);
                const float rby = fminf(bi.w, bj.w);
                const float wq = fmaxf(rbx - ltx + 1.0f, 0.0f);
                const float hq = fmaxf(rby - lty + 1.0f, 0.0f);
                const float inter = wq * hq;
                const float iou = inter / (areai + areaj - inter);
                if (iou > NMS_THRESH) mymask |= (1ull << i);
            }
        }
        // resolve in every wave; only wave-0 results are used (tid<cnt<=64)
        unsigned long long suppbits = 0ull;
        for (int i = 0; i < cnt; ++i) {
            if (!((suppbits >> i) & 1ull)) {
                const unsigned long long vote = __ballot((mymask >> i) & 1ull);
                suppbits |= vote;
            }
        }
        unsigned long long kb = ~suppbits;
        if (cnt < 64) kb &= ((1ull << cnt) - 1ull);
        const int c2 = __popcll(kb);

        if (tid == 0) gcnt[cls] = c2;
        if (tid < cnt && !((suppbits >> tid) & 1ull)) {
            const int kr = __popcll(kb & ((1ull << tid) - 1ull));
            const int slot = cls * DET + kr;
            const unsigned int bits = (unsigned int)(key[tid] >> 16);
            gkeys[slot] = ((unsigned long long)bits << 16) |
                          (unsigned long long)(65535 - slot);
            gboxes[slot] = vbox[tid];
        }
    } else {
        // ===================== SLOW PATH: cnt>64 ============================
        int msz = 1;
        while (msz < cnt) msz <<= 1;
        for (int t = cnt + tid; t < msz; t += NT) key[t] = 0ull;
        __syncthreads();

        for (int k = 2; k <= msz; k <<= 1) {
            for (int jj = k >> 1; jj > 0; jj >>= 1) {
                for (int t = tid; t < msz; t += NT) {
                    const int ixj = t ^ jj;
                    if (ixj > t) {
                        const unsigned long long a = key[t], b = key[ixj];
                        const bool tAfter = (a < b);
                        const bool dirAsc = ((t & k) == 0);
                        if (dirAsc ? tAfter : !tAfter) { key[t] = b; key[ixj] = a; }
                    }
                }
                __syncthreads();
            }
        }

        for (int t = tid; t < cnt; t += NT) {
            const int id = 1023 - (int)(key[t] & 0xFFFFull);
            const float4 p = ((const float4*)props)[id];
            const float w  = p.z - p.x + 1.0f;
            const float h  = p.w - p.y + 1.0f;
            const float cx = p.x + 0.5f * w;
            const float cy = p.y + 0.5f * h;

            const float4 r = ((const float4*)rel)[id * NC + (cls + 1)];
            const float dx = r.x / 10.0f;
            const float dy = r.y / 10.0f;
            const float dw = fminf(r.z / 5.0f, BBOX_CLIP);
            const float dh = fminf(r.w / 5.0f, BBOX_CLIP);

            const float pcx = dx * w + cx;
            const float pcy = dy * h + cy;
            const float pw  = expf(dw) * w;
            const float ph  = expf(dh) * h;

            float bx1 = pcx - 0.5f * pw;
            float by1 = pcy - 0.5f * ph;
            float bx2 = pcx + 0.5f * pw - 1.0f;
            float by2 = pcy + 0.5f * ph - 1.0f;

            bx1 = fminf(fmaxf(bx1, 0.0f), (float)(IMG_W - 1));
            bx2 = fminf(fmaxf(bx2, 0.0f), (float)(IMG_W - 1));
            by1 = fminf(fmaxf(by1, 0.0f), (float)(IMG_H - 1));
            by2 = fminf(fmaxf(by2, 0.0f), (float)(IMG_H - 1));

            vbox[t] = make_float4(bx1, by1, bx2, by2);
            supp[t] = 0;
        }
        __syncthreads();

        for (int i = 0; i < cnt; ++i) {
            if (!supp[i]) {
                const float4 bi = vbox[i];
                const float areai = (bi.z - bi.x + 1.0f) * (bi.w - bi.y + 1.0f);
                for (int t = i + 1 + tid; t < cnt; t += NT) {
                    const float4 bj = vbox[t];
                    const float areaj = (bj.z - bj.x + 1.0f) * (bj.w - bj.y + 1.0f);
                    const float ltx = fmaxf(bi.x, bj.x);
                    const float lty = fmaxf(bi.y, bj.y);
                    const float rbx = fminf(bi.z, bj.z);
                    const float rby = fminf(bi.w, bj.w);
                    const float wq = fmaxf(rbx - ltx + 1.0f, 0.0f);
                    const float hq = fmaxf(rby - lty + 1.0f, 0.0f);
                    const float inter = wq * hq;
                    const float iou = inter / (areai + areaj - inter);
                    if (iou > NMS_THRESH) supp[t] = 1;
                }
            }
            __syncthreads();
        }

        if (tid == 0) {
            int c2 = 0;
            for (int r = 0; r < cnt && c2 < DET; ++r)
                if (!supp[r]) keptRank[c2++] = r;
            keptCnt = c2;
            gcnt[cls] = c2;
        }
        __syncthreads();

        const int kc = keptCnt;
        for (int t = tid; t < kc; t += NT) {
            const int r = keptRank[t];
            const int slot = cls * DET + t;
            const unsigned int bits = (unsigned int)(key[r] >> 16);
            gkeys[slot] = ((unsigned long long)bits << 16) |
                          (unsigned long long)(65535 - slot);
            gboxes[slot] = vbox[r];
        }
    }

    // ---------------- last-block election (NO spinning) ---------------------
    __syncthreads();   // all this block's writes drained before the release
    if (tid == 0) {
        const int prev = __hip_atomic_fetch_add(done, 1, __ATOMIC_RELEASE,
                                                __HIP_MEMORY_SCOPE_AGENT);
        const int last = (prev == CF - 1);
        if (last) {
            // acquire pairing with all 80 releases (release-sequence on done);
            // loop body never executes (we are the last) but forces the load.
            while (__hip_atomic_load(done, __ATOMIC_ACQUIRE,
                                     __HIP_MEMORY_SCOPE_AGENT) < CF) {}
        }
        lastSh = last;
    }
    __syncthreads();
    if (!lastSh) return;   // 79 blocks retire immediately

    // ---------------- Phase T: single-block histogram-select topk -----------
    if (tid < CF) cshare[tid] = gcnt[tid];
    __syncthreads();
    if (tid <= CF) {
        int acc = 0;
        for (int i = 0; i < tid; ++i) acc += cshare[i];   // independent loads
        cbase[tid] = acc;
    }
    for (int t = tid; t < HB; t += NT) hist[t] = 0;
    __syncthreads();
    const int K = cbase[CF];

    // flat parallel gather of the compacted key array (coalesced, ~16 iters)
    unsigned long long* keysh = (unsigned long long*)smem;   // reuses phase-B
    for (int g = tid; g < NCAND; g += NT) {
        const int c = g / DET;          // const-div -> magic mul
        const int j = g - c * DET;
        if (j < cshare[c]) keysh[cbase[c] + j] = gkeys[g];
    }
    __syncthreads();

    // histogram over monotone score-bit buckets
    for (int t = tid; t < K; t += NT) atomicAdd(&hist[bucketOf(keysh[t])], 1);
    __syncthreads();

    // inclusive suffix counts via shuffles: hist[b] := #{keys, bucket >= b}.
    // thread t owns buckets {2t, 2t+1}; pair sums -> in-wave suffix scan in
    // registers -> 8 wave totals -> cross-wave add. No LDS dependency chains.
    {
        const int lane = tid & 63;
        const int wv   = tid >> 6;
        const int h0 = hist[2 * tid];
        const int h1 = hist[2 * tid + 1];
        int v = h0 + h1;
        #pragma unroll
        for (int off = 1; off < 64; off <<= 1) {
            const int src = lane + off;
            const int o = __shfl(v, (src < 64) ? src : lane, 64);
            v += (src < 64) ? o : 0;
        }
        // v = inclusive suffix over this wave's pair sums; lane 0 = wave total
        if (lane == 0) wtot[wv] = v;
        __syncthreads();
        int wa = 0;
        #pragma unroll
        for (int w = 0; w < NT / 64; ++w) wa += (w > wv) ? wtot[w] : 0;
        const int T = v + wa;          // inclusive thread-suffix across block
        hist[2 * tid]     = T;         // S[2t]
        hist[2 * tid + 1] = T - h0;    // S[2t+1]
    }
    if (tid == 0) qnSh = 0;
    __syncthreads();

    // qualifiers: candidates whose strictly-above-bucket count < DET
    // (every final rank<DET winner qualifies: rank >= S[b+1])
    for (int t = tid; t < K; t += NT) {
        const int b = bucketOf(keysh[t]);
        const int above = (b + 1 < HB) ? hist[b + 1] : 0;
        if (above < DET) qidx[atomicAdd(&qnSh, 1)] = t;
    }
    __syncthreads();
    const int qn = qnSh;

    // exact rank = above-bucket count + same-bucket greater keys (all of which
    // are themselves qualifiers, since qualification depends only on bucket)
    for (int q = tid; q < qn; q += NT) {
        const unsigned long long kq = keysh[qidx[q]];
        const int bq = bucketOf(kq);
        int rank = (bq + 1 < HB) ? hist[bq + 1] : 0;
        for (int p = 0; p < qn; ++p) {
            const unsigned long long kp2 = keysh[qidx[p]];   // LDS broadcast
            if (kp2 > kq && bucketOf(kp2) == bq) ++rank;
        }
        if (rank < DET) {
            const float sc  = __uint_as_float((unsigned)(kq >> 16));
            const int  slot = 65535 - (int)(kq & 0xFFFFull);
            const float4 bb = gboxes[slot];
            out[rank * 4 + 0] = bb.x;
            out[rank * 4 + 1] = bb.y;
            out[rank * 4 + 2] = bb.z;
            out[rank * 4 + 3] = bb.w;
            out[4 * DET + rank] = sc;                       // score (>0 always)
            out[5 * DET + rank] = (float)(slot / DET + 1);  // label
        }
    }
}

// ---------------------------------------------------------------------------
extern "C" void kernel_launch(void* const* d_in, const int* in_sizes, int n_in,
                              void* d_out, int out_size, void* d_ws, size_t ws_size,
                              hipStream_t stream) {
    (void)in_sizes; (void)n_in; (void)out_size; (void)ws_size;

    const float* class_logits   = (const float*)d_in[0];  // [NP, NC]
    const float* box_regression = (const float*)d_in[1];  // [NP, 4*NC]
    const float* proposals      = (const float*)d_in[2];  // [NP, 4]
    float* out = (float*)d_out;                           // 600 floats

    // Workspace layout (float units; all offsets 16B-aligned)
    float* ws        = (float*)d_ws;
    float* gboxes_f  = ws;                                    // NCAND*4 = 32000
    float* gkeys_f   = gboxes_f + (size_t)NCAND * 4;          // NCAND*2 = 16000
    float* scores_fg = gkeys_f + (size_t)NCAND * 2;           // CF*NP   = 81920
    int*   gcnt      = (int*)(scores_fg + (size_t)CF * NP);   // CF ints
    int*   done      = gcnt + CF;                             // 1 int

    unsigned long long* gkeys = (unsigned long long*)gkeys_f;
    float4* gboxes = (float4*)gboxes_f;

    softmax_kernel<<<dim3(NP / 4), dim3(256), 0, stream>>>(
        class_logits, scores_fg, out, done);

    nms_topk_kernel<<<dim3(CF), dim3(NT), 0, stream>>>(
        scores_fg, box_regression, proposals, gkeys, gboxes, gcnt, done, out);
}